// Round 2
// baseline (519.741 us; speedup 1.0000x reference)
//
#include <hip/hip_runtime.h>
#include <hip/hip_fp16.h>

// Ontomap: loss = sum((n2f@n_e - f_e)^2) + sum((m2f@m_e - f_e)^2)
// B = 1,048,576, D = 64.
// Round 12: f-bucket sort. R11 showed the kernel is capped on L2-miss
// throughput (doubling waves gave only +13%); the lever left is MISS COUNT.
// Bucket-sorting samples by pos_f>>6 makes the f-gather L1/L2-resident per
// block (4KB slabs) and shrinks the random footprint to nci8 only (9.6MB,
// hit 42% vs 25%). Predicted misses 2.42M -> ~1.3M lines. Pipeline:
// convert(+zero cnt,out) -> hist -> scan -> scatter -> main(q).
// Gated on ws >= tables(16MB)+perm(12MB)+counters(100KB); falls back to the
// R11 path, then to the f32 path. Per-sample numerics unchanged (fp8).

typedef _Float16 half8 __attribute__((ext_vector_type(8)));
typedef __fp16  fp16x2 __attribute__((ext_vector_type(2)));
typedef float floatx16 __attribute__((ext_vector_type(16)));

#define NBLOCKS 2048
#define SPB 128                 // samples per block-iteration: 4 waves * 32
#define NCI_ELEMS 9600000       // 150000 * 64
#define FMA_ELEMS 6400000       // 100000 * 64

#define NBUCK_SHIFT 6
#define NBUCKETS 1563           // ceil(100000 / 64)
#define CNT_STRIDE 16           // one counter per 64B line (atomics contention)

__device__ inline half8 cvt8(float4 a, float4 b) {
    union { half8 h; fp16x2 h2[4]; } u;
    u.h2[0] = __builtin_amdgcn_cvt_pkrtz(a.x, a.y);
    u.h2[1] = __builtin_amdgcn_cvt_pkrtz(a.z, a.w);
    u.h2[2] = __builtin_amdgcn_cvt_pkrtz(b.x, b.y);
    u.h2[3] = __builtin_amdgcn_cvt_pkrtz(b.z, b.w);
    return u.h;
}

__device__ inline uint2 pack4(float4 v) {
    union { fp16x2 h2[2]; uint2 u; } p;
    p.h2[0] = __builtin_amdgcn_cvt_pkrtz(v.x, v.y);
    p.h2[1] = __builtin_amdgcn_cvt_pkrtz(v.z, v.w);
    return p.u;
}

// 8 fp32 -> 8 fp8-e4m3 bytes (ascending order).
__device__ inline uint2 pack8_fp8(float4 a, float4 b) {
    int lo = 0, hi = 0;
    lo = __builtin_amdgcn_cvt_pk_fp8_f32(a.x, a.y, lo, false);
    lo = __builtin_amdgcn_cvt_pk_fp8_f32(a.z, a.w, lo, true);
    hi = __builtin_amdgcn_cvt_pk_fp8_f32(b.x, b.y, hi, false);
    hi = __builtin_amdgcn_cvt_pk_fp8_f32(b.z, b.w, hi, true);
    uint2 r; r.x = (unsigned)lo; r.y = (unsigned)hi; return r;
}

__device__ inline long pack8_fp8_l(const float* p) {
    uint2 b = pack8_fp8(*(const float4*)p, *(const float4*)(p + 4));
    return (long)(((unsigned long)b.y << 32) | b.x);
}

// ---- streaming conversion: both tables -> fp8, into workspace.
// Also zeroes the loss accumulator and (if present) the bucket counters.
__global__ __launch_bounds__(256) void convert_kernel(
    const float4* __restrict__ nci, const float4* __restrict__ fma,
    uint4* __restrict__ nci8, uint4* __restrict__ fma8, float* __restrict__ out,
    unsigned* __restrict__ cnt)
{
    const int stride = gridDim.x * blockDim.x;
    const int tid = blockIdx.x * blockDim.x + threadIdx.x;
    if (tid == 0) out[0] = 0.0f;
    if (cnt) {
        for (int i = tid; i < NBUCKETS * CNT_STRIDE; i += stride) cnt[i] = 0u;
    }
    for (int i = tid; i < NCI_ELEMS / 16; i += stride) {
        uint2 lo = pack8_fp8(nci[4 * i],     nci[4 * i + 1]);
        uint2 hi = pack8_fp8(nci[4 * i + 2], nci[4 * i + 3]);
        nci8[i] = make_uint4(lo.x, lo.y, hi.x, hi.y);
    }
    for (int i = tid; i < FMA_ELEMS / 16; i += stride) {
        uint2 lo = pack8_fp8(fma[4 * i],     fma[4 * i + 1]);
        uint2 hi = pack8_fp8(fma[4 * i + 2], fma[4 * i + 3]);
        fma8[i] = make_uint4(lo.x, lo.y, hi.x, hi.y);
    }
}

// ---- bucket histogram over pos_f (padded counters: 1 per 64B line).
__global__ __launch_bounds__(256) void hist_kernel(
    const int* __restrict__ pf, unsigned* __restrict__ cnt, int B)
{
    const int stride = gridDim.x * blockDim.x;
    for (int i = blockIdx.x * blockDim.x + threadIdx.x; i < B; i += stride)
        atomicAdd(&cnt[(pf[i] >> NBUCK_SHIFT) * CNT_STRIDE], 1u);
}

// ---- exclusive prefix over the 1563 padded counters, in place. One block.
__global__ __launch_bounds__(256) void scan_kernel(unsigned* __restrict__ cnt)
{
    __shared__ unsigned part[256];
    const int t = threadIdx.x;
    const int base = t * 7;                    // 256*7 = 1792 >= 1563
    unsigned s = 0;
#pragma unroll
    for (int j = 0; j < 7; ++j) {
        int b = base + j;
        if (b < NBUCKETS) s += cnt[b * CNT_STRIDE];
    }
    part[t] = s;
    __syncthreads();
    for (int off = 1; off < 256; off <<= 1) {
        unsigned v = (t >= off) ? part[t - off] : 0u;
        __syncthreads();
        part[t] += v;
        __syncthreads();
    }
    unsigned run = (t == 0) ? 0u : part[t - 1];  // exclusive prefix
#pragma unroll
    for (int j = 0; j < 7; ++j) {
        int b = base + j;
        if (b < NBUCKETS) {
            unsigned c = cnt[b * CNT_STRIDE];
            cnt[b * CNT_STRIDE] = run;
            run += c;
        }
    }
}

// ---- scatter samples into f-bucket order (dense permutation).
__global__ __launch_bounds__(256) void scatter_kernel(
    const int* __restrict__ pn, const int* __restrict__ pm,
    const int* __restrict__ pf, unsigned* __restrict__ cnt,
    int* __restrict__ sn, int* __restrict__ sm, int* __restrict__ sf, int B)
{
    const int i = blockIdx.x * blockDim.x + threadIdx.x;
    if (i >= B) return;
    const int n = pn[i], m = pm[i], f = pf[i];
    const unsigned p = atomicAdd(&cnt[(f >> NBUCK_SHIFT) * CNT_STRIDE], 1u);
    sn[p] = n; sm[p] = m; sf[p] = f;
}

// ---- main kernel: fp8 tables, K-remapped dwordx4 gathers, sequential tiles.
// CONTIG=1: block b owns samples [b*SPB*iters, (b+1)*SPB*iters) (sorted path);
// CONTIG=0: R11 strided mapping (unsorted path).
template <int CONTIG>
__global__ __launch_bounds__(256, 8) void ontomap_kernel_q(
    const int* __restrict__ pos_n, const int* __restrict__ pos_m,
    const int* __restrict__ pos_f,
    const unsigned char* __restrict__ nci8, const unsigned char* __restrict__ fma8,
    const float* __restrict__ n2f, const float* __restrict__ m2f,
    float* __restrict__ out, int iters)
{
    const int lane = threadIdx.x & 63;
    const int wave = threadIdx.x >> 6;
    const int l31  = lane & 31;
    const int hi   = lane >> 5;
    const int hoff = hi * 32;     // this lane's contiguous 32-byte half-row

    // B fragments under the K-remap k = hoff + t*8 + j:
    // MFMA step t, B slot (hi,j) = M[n][hoff + t*8 + j], n = nt*32 + l31.
    long Bn[2][4], Bm[2][4];
#pragma unroll
    for (int nt = 0; nt < 2; ++nt) {
#pragma unroll
        for (int t = 0; t < 4; ++t) {
            Bn[nt][t] = pack8_fp8_l(n2f + (nt * 32 + l31) * 64 + hoff + t * 8);
            Bm[nt][t] = pack8_fp8_l(m2f + (nt * 32 + l31) * 64 + hoff + t * 8);
        }
    }

    // -I fragments (fp8 0xB8 = -1.0 e4m3). Under the remap, tile0's diagonal
    // lives in hi=0 slots, tile1's in hi=1 slots: step t has -1 at byte
    // j = l31 - t*8 when 0 <= j < 8.  (Verified correct in round 9.)
    long If0[4], If1[4];
#pragma unroll
    for (int t = 0; t < 4; ++t) {
        const unsigned j = (unsigned)(l31 - t * 8);
        const long pat = (j < 8) ? (long)(0xB8ULL << (8 * j)) : 0L;
        If0[t] = hi ? 0L : pat;
        If1[t] = hi ? pat : 0L;
    }

    float l0 = 0.0f, l1 = 0.0f, l2 = 0.0f, l3 = 0.0f;

    const int sbase = CONTIG ? (blockIdx.x * (SPB * iters) + wave * 32 + l31)
                             : (blockIdx.x * SPB + wave * 32 + l31);
    int in_, im_, if_;
    in_ = pos_n[sbase]; im_ = pos_m[sbase]; if_ = pos_f[sbase];

#pragma unroll 1
    for (int it = 0; it < iters; ++it) {
        const int in0 = in_, im0 = im_, if0 = if_;
        if (it + 1 < iters) {
            const int s = CONTIG ? (sbase + (it + 1) * SPB)
                                 : (sbase + (it + 1) * NBLOCKS * SPB);
            in_ = pos_n[s]; im_ = pos_m[s]; if_ = pos_f[s];
        }

        // ---- 6 independent dwordx4 gathers (32 contiguous B per lane).
        // Order: An, Ff, Am -- so Am is still in flight during n-tiles.
        const unsigned char* pn = nci8 + (long)in0 * 64 + hoff;
        const unsigned char* pf = fma8 + (long)if0 * 64 + hoff;
        const unsigned char* pm = nci8 + (long)im0 * 64 + hoff;

        ulonglong2 n01 = *(const ulonglong2*)pn;
        ulonglong2 n23 = *(const ulonglong2*)(pn + 16);
        ulonglong2 f01 = *(const ulonglong2*)pf;
        ulonglong2 f23 = *(const ulonglong2*)(pf + 16);
        ulonglong2 m01 = *(const ulonglong2*)pm;
        ulonglong2 m23 = *(const ulonglong2*)(pm + 16);

        const long An[4] = {(long)n01.x, (long)n01.y, (long)n23.x, (long)n23.y};
        const long Ff[4] = {(long)f01.x, (long)f01.y, (long)f23.x, (long)f23.y};
        const long Am[4] = {(long)m01.x, (long)m01.y, (long)m23.x, (long)m23.y};

        // ---- sequential tiles: one 16-reg accumulator live at a time.
        {   // n-loss, tile 0 (dims 0..31)
            floatx16 a{};
#pragma unroll
            for (int t = 0; t < 4; ++t)
                a = __builtin_amdgcn_mfma_f32_32x32x16_fp8_fp8(An[t], Bn[0][t], a, 0, 0, 0);
#pragma unroll
            for (int t = 0; t < 4; ++t)
                a = __builtin_amdgcn_mfma_f32_32x32x16_fp8_fp8(Ff[t], If0[t], a, 0, 0, 0);
#pragma unroll
            for (int r = 0; r < 16; r += 4) {
                l0 = fmaf(a[r],     a[r],     l0);
                l1 = fmaf(a[r + 1], a[r + 1], l1);
                l2 = fmaf(a[r + 2], a[r + 2], l2);
                l3 = fmaf(a[r + 3], a[r + 3], l3);
            }
        }
        {   // n-loss, tile 1 (dims 32..63)
            floatx16 a{};
#pragma unroll
            for (int t = 0; t < 4; ++t)
                a = __builtin_amdgcn_mfma_f32_32x32x16_fp8_fp8(An[t], Bn[1][t], a, 0, 0, 0);
#pragma unroll
            for (int t = 0; t < 4; ++t)
                a = __builtin_amdgcn_mfma_f32_32x32x16_fp8_fp8(Ff[t], If1[t], a, 0, 0, 0);
#pragma unroll
            for (int r = 0; r < 16; r += 4) {
                l0 = fmaf(a[r],     a[r],     l0);
                l1 = fmaf(a[r + 1], a[r + 1], l1);
                l2 = fmaf(a[r + 2], a[r + 2], l2);
                l3 = fmaf(a[r + 3], a[r + 3], l3);
            }
        }
        {   // m-loss, tile 0
            floatx16 a{};
#pragma unroll
            for (int t = 0; t < 4; ++t)
                a = __builtin_amdgcn_mfma_f32_32x32x16_fp8_fp8(Am[t], Bm[0][t], a, 0, 0, 0);
#pragma unroll
            for (int t = 0; t < 4; ++t)
                a = __builtin_amdgcn_mfma_f32_32x32x16_fp8_fp8(Ff[t], If0[t], a, 0, 0, 0);
#pragma unroll
            for (int r = 0; r < 16; r += 4) {
                l0 = fmaf(a[r],     a[r],     l0);
                l1 = fmaf(a[r + 1], a[r + 1], l1);
                l2 = fmaf(a[r + 2], a[r + 2], l2);
                l3 = fmaf(a[r + 3], a[r + 3], l3);
            }
        }
        {   // m-loss, tile 1
            floatx16 a{};
#pragma unroll
            for (int t = 0; t < 4; ++t)
                a = __builtin_amdgcn_mfma_f32_32x32x16_fp8_fp8(Am[t], Bm[1][t], a, 0, 0, 0);
#pragma unroll
            for (int t = 0; t < 4; ++t)
                a = __builtin_amdgcn_mfma_f32_32x32x16_fp8_fp8(Ff[t], If1[t], a, 0, 0, 0);
#pragma unroll
            for (int r = 0; r < 16; r += 4) {
                l0 = fmaf(a[r],     a[r],     l0);
                l1 = fmaf(a[r + 1], a[r + 1], l1);
                l2 = fmaf(a[r + 2], a[r + 2], l2);
                l3 = fmaf(a[r + 3], a[r + 3], l3);
            }
        }
    }

    float loss = (l0 + l1) + (l2 + l3);
#pragma unroll
    for (int o = 32; o > 0; o >>= 1) loss += __shfl_xor(loss, o, 64);

    // block-level reduction: 1 atomic per block instead of 4.
    __shared__ float red[4];
    if (lane == 0) red[wave] = loss;
    __syncthreads();
    if (threadIdx.x == 0)
        atomicAdd(out, (red[0] + red[1]) + (red[2] + red[3]));
}

// ---- fallback: fp32 tables with LDS staging (round-4 style), if ws too small.
#define ROW_BYTES 144
__global__ __launch_bounds__(256, 2) void ontomap_kernel_f32(
    const int* __restrict__ pos_n, const int* __restrict__ pos_m,
    const int* __restrict__ pos_f,
    const float* __restrict__ nci, const float* __restrict__ fma_emb,
    const float* __restrict__ n2f, const float* __restrict__ m2f,
    float* __restrict__ out, int iters)
{
    __shared__ char lds[4 * 2 * 32 * ROW_BYTES];

    const int lane = threadIdx.x & 63;
    const int wave = threadIdx.x >> 6;
    const int l31  = lane & 31;
    const int hi   = lane >> 5;
    const int kbase = hi * 8;
    const int srow   = lane >> 4;
    const int schunk = lane & 15;

    char* const nbase = lds + wave * (2 * 32 * ROW_BYTES);
    char* const mbase = nbase + 32 * ROW_BYTES;

    half8 Bn[2][4], Bm[2][4];
#pragma unroll
    for (int nt = 0; nt < 2; ++nt) {
#pragma unroll
        for (int t = 0; t < 4; ++t) {
            const float* p = n2f + (nt * 32 + l31) * 64 + t * 16 + kbase;
            Bn[nt][t] = cvt8(*(const float4*)p, *(const float4*)(p + 4));
            const float* q = m2f + (nt * 32 + l31) * 64 + t * 16 + kbase;
            Bm[nt][t] = cvt8(*(const float4*)q, *(const float4*)(q + 4));
        }
    }

    float loss = 0.0f;
    int in_, im_, if_;
    {
        int s = blockIdx.x * SPB + wave * 32 + l31;
        in_ = pos_n[s]; im_ = pos_m[s]; if_ = pos_f[s];
    }

#pragma unroll 1
    for (int it = 0; it < iters; ++it) {
        const int in0 = in_, im0 = im_, if0 = if_;
        if (it + 1 < iters) {
            int s = ((it + 1) * NBLOCKS + blockIdx.x) * SPB + wave * 32 + l31;
            in_ = pos_n[s]; im_ = pos_m[s]; if_ = pos_f[s];
        }

#pragma unroll
        for (int i = 0; i < 8; ++i) {
            const int rl = i * 4 + srow;
            const int rn = __shfl(in0, rl, 64);
            float4 v = ((const float4*)(nci + (long)rn * 64))[schunk];
            *(uint2*)(nbase + rl * ROW_BYTES + schunk * 8) = pack4(v);
            const int rm = __shfl(im0, rl, 64);
            float4 w = ((const float4*)(nci + (long)rm * 64))[schunk];
            *(uint2*)(mbase + rl * ROW_BYTES + schunk * 8) = pack4(w);
        }
        asm volatile("" ::: "memory");

        floatx16 aN0{}, aN1{}, aM0{}, aM1{};
#pragma unroll
        for (int t = 0; t < 4; ++t) {
            half8 aF = *(const half8*)(nbase + l31 * ROW_BYTES + t * 32 + hi * 16);
            aN0 = __builtin_amdgcn_mfma_f32_32x32x16_f16(aF, Bn[0][t], aN0, 0, 0, 0);
            aN1 = __builtin_amdgcn_mfma_f32_32x32x16_f16(aF, Bn[1][t], aN1, 0, 0, 0);
            half8 bF = *(const half8*)(mbase + l31 * ROW_BYTES + t * 32 + hi * 16);
            aM0 = __builtin_amdgcn_mfma_f32_32x32x16_f16(bF, Bm[0][t], aM0, 0, 0, 0);
            aM1 = __builtin_amdgcn_mfma_f32_32x32x16_f16(bF, Bm[1][t], aM1, 0, 0, 0);
        }

#pragma unroll
        for (int r = 0; r < 16; ++r) {
            const int mrow = (r & 3) + 8 * (r >> 2) + 4 * hi;
            const int fid  = __shfl(if0, mrow, 64);
            const float* pf = fma_emb + (long)fid * 64 + l31;
            const float f0 = pf[0];
            const float f1 = pf[32];
            float d;
            d = aN0[r] - f0; loss = fmaf(d, d, loss);
            d = aM0[r] - f0; loss = fmaf(d, d, loss);
            d = aN1[r] - f1; loss = fmaf(d, d, loss);
            d = aM1[r] - f1; loss = fmaf(d, d, loss);
        }
    }

#pragma unroll
    for (int o = 32; o > 0; o >>= 1) loss += __shfl_xor(loss, o, 64);
    if (lane == 0) atomicAdd(out, loss);
}

extern "C" void kernel_launch(void* const* d_in, const int* in_sizes, int n_in,
                              void* d_out, int out_size, void* d_ws, size_t ws_size,
                              hipStream_t stream) {
    const int*   pos_n   = (const int*)d_in[0];
    const int*   pos_m   = (const int*)d_in[1];
    const int*   pos_f   = (const int*)d_in[2];
    const float* nci_emb = (const float*)d_in[3];
    const float* fma_emb = (const float*)d_in[4];
    const float* n2f_mat = (const float*)d_in[5];
    const float* m2f_mat = (const float*)d_in[6];
    float* out = (float*)d_out;

    const int B = in_sizes[0];
    const int iters = B / (NBLOCKS * SPB);  // 1,048,576 -> 4

    const size_t TBL  = (size_t)NCI_ELEMS + (size_t)FMA_ELEMS;      // 16,000,000
    const size_t PERM = 3ull * (size_t)B * sizeof(int);             // 12,582,912
    const size_t CNTB = (size_t)NBUCKETS * CNT_STRIDE * sizeof(unsigned);

    if (ws_size >= TBL + PERM + CNTB && iters * NBLOCKS * SPB == B) {
        // ---- sorted fp8 path.
        unsigned char* nci8 = (unsigned char*)d_ws;
        unsigned char* fma8 = nci8 + NCI_ELEMS;      // 9,600,000 is 64B-aligned
        int* sn = (int*)(nci8 + TBL);                // 16,000,000 is 64B-aligned
        int* sm = sn + B;
        int* sf = sm + B;
        unsigned* cnt = (unsigned*)(sf + B);         // 28,582,912 is 64B-aligned

        convert_kernel<<<2048, 256, 0, stream>>>(
            (const float4*)nci_emb, (const float4*)fma_emb,
            (uint4*)nci8, (uint4*)fma8, out, cnt);
        hist_kernel<<<1024, 256, 0, stream>>>(pos_f, cnt, B);
        scan_kernel<<<1, 256, 0, stream>>>(cnt);
        scatter_kernel<<<(B + 255) / 256, 256, 0, stream>>>(
            pos_n, pos_m, pos_f, cnt, sn, sm, sf, B);
        ontomap_kernel_q<1><<<NBLOCKS, 256, 0, stream>>>(
            sn, sm, sf, nci8, fma8, n2f_mat, m2f_mat, out, iters);
    } else if (ws_size >= TBL) {
        // ---- unsorted fp8 path (R11).
        unsigned char* nci8 = (unsigned char*)d_ws;
        unsigned char* fma8 = nci8 + NCI_ELEMS;
        convert_kernel<<<2048, 256, 0, stream>>>(
            (const float4*)nci_emb, (const float4*)fma_emb,
            (uint4*)nci8, (uint4*)fma8, out, (unsigned*)nullptr);
        ontomap_kernel_q<0><<<NBLOCKS, 256, 0, stream>>>(
            pos_n, pos_m, pos_f, nci8, fma8, n2f_mat, m2f_mat, out, iters);
    } else {
        (void)hipMemsetAsync(out, 0, sizeof(float), stream);
        ontomap_kernel_f32<<<NBLOCKS, 256, 0, stream>>>(
            pos_n, pos_m, pos_f, nci_emb, fma_emb, n2f_mat, m2f_mat, out, iters);
    }
}

// Round 3
// 302.656 us; speedup vs baseline: 1.7173x; 1.7173x over previous
//
#include <hip/hip_runtime.h>
#include <hip/hip_fp16.h>

// Ontomap: loss = sum((n2f@n_e - f_e)^2) + sum((m2f@m_e - f_e)^2)
// B = 1,048,576, D = 64.
// Round 13: R12 (f-bucket sort) with the launch_bounds regression fixed.
// R12 used __launch_bounds__(256,8) -> VGPR capped at 32 -> full scratch
// spill (WRITE_SIZE 510MB, 280us). Reverted to (256,4) (VGPR=64, no spill,
// verified through R11). Sort pipeline unchanged: convert -> hist -> scan ->
// scatter -> main(q, CONTIG=1). Sorting by pos_f>>6 makes f-gathers
// L1/L2-resident and shrinks the random footprint to nci8 (9.6MB).

typedef _Float16 half8 __attribute__((ext_vector_type(8)));
typedef __fp16  fp16x2 __attribute__((ext_vector_type(2)));
typedef float floatx16 __attribute__((ext_vector_type(16)));

#define NBLOCKS 2048
#define SPB 128                 // samples per block-iteration: 4 waves * 32
#define NCI_ELEMS 9600000       // 150000 * 64
#define FMA_ELEMS 6400000       // 100000 * 64

#define NBUCK_SHIFT 6
#define NBUCKETS 1563           // ceil(100000 / 64)
#define CNT_STRIDE 16           // one counter per 64B line (atomics contention)

__device__ inline half8 cvt8(float4 a, float4 b) {
    union { half8 h; fp16x2 h2[4]; } u;
    u.h2[0] = __builtin_amdgcn_cvt_pkrtz(a.x, a.y);
    u.h2[1] = __builtin_amdgcn_cvt_pkrtz(a.z, a.w);
    u.h2[2] = __builtin_amdgcn_cvt_pkrtz(b.x, b.y);
    u.h2[3] = __builtin_amdgcn_cvt_pkrtz(b.z, b.w);
    return u.h;
}

__device__ inline uint2 pack4(float4 v) {
    union { fp16x2 h2[2]; uint2 u; } p;
    p.h2[0] = __builtin_amdgcn_cvt_pkrtz(v.x, v.y);
    p.h2[1] = __builtin_amdgcn_cvt_pkrtz(v.z, v.w);
    return p.u;
}

// 8 fp32 -> 8 fp8-e4m3 bytes (ascending order).
__device__ inline uint2 pack8_fp8(float4 a, float4 b) {
    int lo = 0, hi = 0;
    lo = __builtin_amdgcn_cvt_pk_fp8_f32(a.x, a.y, lo, false);
    lo = __builtin_amdgcn_cvt_pk_fp8_f32(a.z, a.w, lo, true);
    hi = __builtin_amdgcn_cvt_pk_fp8_f32(b.x, b.y, hi, false);
    hi = __builtin_amdgcn_cvt_pk_fp8_f32(b.z, b.w, hi, true);
    uint2 r; r.x = (unsigned)lo; r.y = (unsigned)hi; return r;
}

__device__ inline long pack8_fp8_l(const float* p) {
    uint2 b = pack8_fp8(*(const float4*)p, *(const float4*)(p + 4));
    return (long)(((unsigned long)b.y << 32) | b.x);
}

// ---- streaming conversion: both tables -> fp8, into workspace.
// Also zeroes the loss accumulator and (if present) the bucket counters.
__global__ __launch_bounds__(256) void convert_kernel(
    const float4* __restrict__ nci, const float4* __restrict__ fma,
    uint4* __restrict__ nci8, uint4* __restrict__ fma8, float* __restrict__ out,
    unsigned* __restrict__ cnt)
{
    const int stride = gridDim.x * blockDim.x;
    const int tid = blockIdx.x * blockDim.x + threadIdx.x;
    if (tid == 0) out[0] = 0.0f;
    if (cnt) {
        for (int i = tid; i < NBUCKETS * CNT_STRIDE; i += stride) cnt[i] = 0u;
    }
    for (int i = tid; i < NCI_ELEMS / 16; i += stride) {
        uint2 lo = pack8_fp8(nci[4 * i],     nci[4 * i + 1]);
        uint2 hi = pack8_fp8(nci[4 * i + 2], nci[4 * i + 3]);
        nci8[i] = make_uint4(lo.x, lo.y, hi.x, hi.y);
    }
    for (int i = tid; i < FMA_ELEMS / 16; i += stride) {
        uint2 lo = pack8_fp8(fma[4 * i],     fma[4 * i + 1]);
        uint2 hi = pack8_fp8(fma[4 * i + 2], fma[4 * i + 3]);
        fma8[i] = make_uint4(lo.x, lo.y, hi.x, hi.y);
    }
}

// ---- bucket histogram over pos_f (padded counters: 1 per 64B line).
__global__ __launch_bounds__(256) void hist_kernel(
    const int* __restrict__ pf, unsigned* __restrict__ cnt, int B)
{
    const int stride = gridDim.x * blockDim.x;
    for (int i = blockIdx.x * blockDim.x + threadIdx.x; i < B; i += stride)
        atomicAdd(&cnt[(pf[i] >> NBUCK_SHIFT) * CNT_STRIDE], 1u);
}

// ---- exclusive prefix over the 1563 padded counters, in place. One block.
__global__ __launch_bounds__(256) void scan_kernel(unsigned* __restrict__ cnt)
{
    __shared__ unsigned part[256];
    const int t = threadIdx.x;
    const int base = t * 7;                    // 256*7 = 1792 >= 1563
    unsigned s = 0;
#pragma unroll
    for (int j = 0; j < 7; ++j) {
        int b = base + j;
        if (b < NBUCKETS) s += cnt[b * CNT_STRIDE];
    }
    part[t] = s;
    __syncthreads();
    for (int off = 1; off < 256; off <<= 1) {
        unsigned v = (t >= off) ? part[t - off] : 0u;
        __syncthreads();
        part[t] += v;
        __syncthreads();
    }
    unsigned run = (t == 0) ? 0u : part[t - 1];  // exclusive prefix
#pragma unroll
    for (int j = 0; j < 7; ++j) {
        int b = base + j;
        if (b < NBUCKETS) {
            unsigned c = cnt[b * CNT_STRIDE];
            cnt[b * CNT_STRIDE] = run;
            run += c;
        }
    }
}

// ---- scatter samples into f-bucket order (dense permutation).
__global__ __launch_bounds__(256) void scatter_kernel(
    const int* __restrict__ pn, const int* __restrict__ pm,
    const int* __restrict__ pf, unsigned* __restrict__ cnt,
    int* __restrict__ sn, int* __restrict__ sm, int* __restrict__ sf, int B)
{
    const int i = blockIdx.x * blockDim.x + threadIdx.x;
    if (i >= B) return;
    const int n = pn[i], m = pm[i], f = pf[i];
    const unsigned p = atomicAdd(&cnt[(f >> NBUCK_SHIFT) * CNT_STRIDE], 1u);
    sn[p] = n; sm[p] = m; sf[p] = f;
}

// ---- main kernel: fp8 tables, K-remapped dwordx4 gathers, sequential tiles.
// CONTIG=1: block b owns samples [b*SPB*iters, (b+1)*SPB*iters) (sorted path);
// CONTIG=0: R11 strided mapping (unsorted path).
template <int CONTIG>
__global__ __launch_bounds__(256, 4) void ontomap_kernel_q(
    const int* __restrict__ pos_n, const int* __restrict__ pos_m,
    const int* __restrict__ pos_f,
    const unsigned char* __restrict__ nci8, const unsigned char* __restrict__ fma8,
    const float* __restrict__ n2f, const float* __restrict__ m2f,
    float* __restrict__ out, int iters)
{
    const int lane = threadIdx.x & 63;
    const int wave = threadIdx.x >> 6;
    const int l31  = lane & 31;
    const int hi   = lane >> 5;
    const int hoff = hi * 32;     // this lane's contiguous 32-byte half-row

    // B fragments under the K-remap k = hoff + t*8 + j:
    // MFMA step t, B slot (hi,j) = M[n][hoff + t*8 + j], n = nt*32 + l31.
    long Bn[2][4], Bm[2][4];
#pragma unroll
    for (int nt = 0; nt < 2; ++nt) {
#pragma unroll
        for (int t = 0; t < 4; ++t) {
            Bn[nt][t] = pack8_fp8_l(n2f + (nt * 32 + l31) * 64 + hoff + t * 8);
            Bm[nt][t] = pack8_fp8_l(m2f + (nt * 32 + l31) * 64 + hoff + t * 8);
        }
    }

    // -I fragments (fp8 0xB8 = -1.0 e4m3). Under the remap, tile0's diagonal
    // lives in hi=0 slots, tile1's in hi=1 slots: step t has -1 at byte
    // j = l31 - t*8 when 0 <= j < 8.  (Verified correct in round 9.)
    long If0[4], If1[4];
#pragma unroll
    for (int t = 0; t < 4; ++t) {
        const unsigned j = (unsigned)(l31 - t * 8);
        const long pat = (j < 8) ? (long)(0xB8ULL << (8 * j)) : 0L;
        If0[t] = hi ? 0L : pat;
        If1[t] = hi ? pat : 0L;
    }

    float l0 = 0.0f, l1 = 0.0f, l2 = 0.0f, l3 = 0.0f;

    const int sbase = CONTIG ? (blockIdx.x * (SPB * iters) + wave * 32 + l31)
                             : (blockIdx.x * SPB + wave * 32 + l31);
    int in_, im_, if_;
    in_ = pos_n[sbase]; im_ = pos_m[sbase]; if_ = pos_f[sbase];

#pragma unroll 1
    for (int it = 0; it < iters; ++it) {
        const int in0 = in_, im0 = im_, if0 = if_;
        if (it + 1 < iters) {
            const int s = CONTIG ? (sbase + (it + 1) * SPB)
                                 : (sbase + (it + 1) * NBLOCKS * SPB);
            in_ = pos_n[s]; im_ = pos_m[s]; if_ = pos_f[s];
        }

        // ---- 6 independent dwordx4 gathers (32 contiguous B per lane).
        // Order: An, Ff, Am -- so Am is still in flight during n-tiles.
        const unsigned char* pn = nci8 + (long)in0 * 64 + hoff;
        const unsigned char* pf = fma8 + (long)if0 * 64 + hoff;
        const unsigned char* pm = nci8 + (long)im0 * 64 + hoff;

        ulonglong2 n01 = *(const ulonglong2*)pn;
        ulonglong2 n23 = *(const ulonglong2*)(pn + 16);
        ulonglong2 f01 = *(const ulonglong2*)pf;
        ulonglong2 f23 = *(const ulonglong2*)(pf + 16);
        ulonglong2 m01 = *(const ulonglong2*)pm;
        ulonglong2 m23 = *(const ulonglong2*)(pm + 16);

        const long An[4] = {(long)n01.x, (long)n01.y, (long)n23.x, (long)n23.y};
        const long Ff[4] = {(long)f01.x, (long)f01.y, (long)f23.x, (long)f23.y};
        const long Am[4] = {(long)m01.x, (long)m01.y, (long)m23.x, (long)m23.y};

        // ---- sequential tiles: one 16-reg accumulator live at a time.
        {   // n-loss, tile 0 (dims 0..31)
            floatx16 a{};
#pragma unroll
            for (int t = 0; t < 4; ++t)
                a = __builtin_amdgcn_mfma_f32_32x32x16_fp8_fp8(An[t], Bn[0][t], a, 0, 0, 0);
#pragma unroll
            for (int t = 0; t < 4; ++t)
                a = __builtin_amdgcn_mfma_f32_32x32x16_fp8_fp8(Ff[t], If0[t], a, 0, 0, 0);
#pragma unroll
            for (int r = 0; r < 16; r += 4) {
                l0 = fmaf(a[r],     a[r],     l0);
                l1 = fmaf(a[r + 1], a[r + 1], l1);
                l2 = fmaf(a[r + 2], a[r + 2], l2);
                l3 = fmaf(a[r + 3], a[r + 3], l3);
            }
        }
        {   // n-loss, tile 1 (dims 32..63)
            floatx16 a{};
#pragma unroll
            for (int t = 0; t < 4; ++t)
                a = __builtin_amdgcn_mfma_f32_32x32x16_fp8_fp8(An[t], Bn[1][t], a, 0, 0, 0);
#pragma unroll
            for (int t = 0; t < 4; ++t)
                a = __builtin_amdgcn_mfma_f32_32x32x16_fp8_fp8(Ff[t], If1[t], a, 0, 0, 0);
#pragma unroll
            for (int r = 0; r < 16; r += 4) {
                l0 = fmaf(a[r],     a[r],     l0);
                l1 = fmaf(a[r + 1], a[r + 1], l1);
                l2 = fmaf(a[r + 2], a[r + 2], l2);
                l3 = fmaf(a[r + 3], a[r + 3], l3);
            }
        }
        {   // m-loss, tile 0
            floatx16 a{};
#pragma unroll
            for (int t = 0; t < 4; ++t)
                a = __builtin_amdgcn_mfma_f32_32x32x16_fp8_fp8(Am[t], Bm[0][t], a, 0, 0, 0);
#pragma unroll
            for (int t = 0; t < 4; ++t)
                a = __builtin_amdgcn_mfma_f32_32x32x16_fp8_fp8(Ff[t], If0[t], a, 0, 0, 0);
#pragma unroll
            for (int r = 0; r < 16; r += 4) {
                l0 = fmaf(a[r],     a[r],     l0);
                l1 = fmaf(a[r + 1], a[r + 1], l1);
                l2 = fmaf(a[r + 2], a[r + 2], l2);
                l3 = fmaf(a[r + 3], a[r + 3], l3);
            }
        }
        {   // m-loss, tile 1
            floatx16 a{};
#pragma unroll
            for (int t = 0; t < 4; ++t)
                a = __builtin_amdgcn_mfma_f32_32x32x16_fp8_fp8(Am[t], Bm[1][t], a, 0, 0, 0);
#pragma unroll
            for (int t = 0; t < 4; ++t)
                a = __builtin_amdgcn_mfma_f32_32x32x16_fp8_fp8(Ff[t], If1[t], a, 0, 0, 0);
#pragma unroll
            for (int r = 0; r < 16; r += 4) {
                l0 = fmaf(a[r],     a[r],     l0);
                l1 = fmaf(a[r + 1], a[r + 1], l1);
                l2 = fmaf(a[r + 2], a[r + 2], l2);
                l3 = fmaf(a[r + 3], a[r + 3], l3);
            }
        }
    }

    float loss = (l0 + l1) + (l2 + l3);
#pragma unroll
    for (int o = 32; o > 0; o >>= 1) loss += __shfl_xor(loss, o, 64);

    // block-level reduction: 1 atomic per block instead of 4.
    __shared__ float red[4];
    if (lane == 0) red[wave] = loss;
    __syncthreads();
    if (threadIdx.x == 0)
        atomicAdd(out, (red[0] + red[1]) + (red[2] + red[3]));
}

// ---- fallback: fp32 tables with LDS staging (round-4 style), if ws too small.
#define ROW_BYTES 144
__global__ __launch_bounds__(256, 2) void ontomap_kernel_f32(
    const int* __restrict__ pos_n, const int* __restrict__ pos_m,
    const int* __restrict__ pos_f,
    const float* __restrict__ nci, const float* __restrict__ fma_emb,
    const float* __restrict__ n2f, const float* __restrict__ m2f,
    float* __restrict__ out, int iters)
{
    __shared__ char lds[4 * 2 * 32 * ROW_BYTES];

    const int lane = threadIdx.x & 63;
    const int wave = threadIdx.x >> 6;
    const int l31  = lane & 31;
    const int hi   = lane >> 5;
    const int kbase = hi * 8;
    const int srow   = lane >> 4;
    const int schunk = lane & 15;

    char* const nbase = lds + wave * (2 * 32 * ROW_BYTES);
    char* const mbase = nbase + 32 * ROW_BYTES;

    half8 Bn[2][4], Bm[2][4];
#pragma unroll
    for (int nt = 0; nt < 2; ++nt) {
#pragma unroll
        for (int t = 0; t < 4; ++t) {
            const float* p = n2f + (nt * 32 + l31) * 64 + t * 16 + kbase;
            Bn[nt][t] = cvt8(*(const float4*)p, *(const float4*)(p + 4));
            const float* q = m2f + (nt * 32 + l31) * 64 + t * 16 + kbase;
            Bm[nt][t] = cvt8(*(const float4*)q, *(const float4*)(q + 4));
        }
    }

    float loss = 0.0f;
    int in_, im_, if_;
    {
        int s = blockIdx.x * SPB + wave * 32 + l31;
        in_ = pos_n[s]; im_ = pos_m[s]; if_ = pos_f[s];
    }

#pragma unroll 1
    for (int it = 0; it < iters; ++it) {
        const int in0 = in_, im0 = im_, if0 = if_;
        if (it + 1 < iters) {
            int s = ((it + 1) * NBLOCKS + blockIdx.x) * SPB + wave * 32 + l31;
            in_ = pos_n[s]; im_ = pos_m[s]; if_ = pos_f[s];
        }

#pragma unroll
        for (int i = 0; i < 8; ++i) {
            const int rl = i * 4 + srow;
            const int rn = __shfl(in0, rl, 64);
            float4 v = ((const float4*)(nci + (long)rn * 64))[schunk];
            *(uint2*)(nbase + rl * ROW_BYTES + schunk * 8) = pack4(v);
            const int rm = __shfl(im0, rl, 64);
            float4 w = ((const float4*)(nci + (long)rm * 64))[schunk];
            *(uint2*)(mbase + rl * ROW_BYTES + schunk * 8) = pack4(w);
        }
        asm volatile("" ::: "memory");

        floatx16 aN0{}, aN1{}, aM0{}, aM1{};
#pragma unroll
        for (int t = 0; t < 4; ++t) {
            half8 aF = *(const half8*)(nbase + l31 * ROW_BYTES + t * 32 + hi * 16);
            aN0 = __builtin_amdgcn_mfma_f32_32x32x16_f16(aF, Bn[0][t], aN0, 0, 0, 0);
            aN1 = __builtin_amdgcn_mfma_f32_32x32x16_f16(aF, Bn[1][t], aN1, 0, 0, 0);
            half8 bF = *(const half8*)(mbase + l31 * ROW_BYTES + t * 32 + hi * 16);
            aM0 = __builtin_amdgcn_mfma_f32_32x32x16_f16(bF, Bm[0][t], aM0, 0, 0, 0);
            aM1 = __builtin_amdgcn_mfma_f32_32x32x16_f16(bF, Bm[1][t], aM1, 0, 0, 0);
        }

#pragma unroll
        for (int r = 0; r < 16; ++r) {
            const int mrow = (r & 3) + 8 * (r >> 2) + 4 * hi;
            const int fid  = __shfl(if0, mrow, 64);
            const float* pf = fma_emb + (long)fid * 64 + l31;
            const float f0 = pf[0];
            const float f1 = pf[32];
            float d;
            d = aN0[r] - f0; loss = fmaf(d, d, loss);
            d = aM0[r] - f0; loss = fmaf(d, d, loss);
            d = aN1[r] - f1; loss = fmaf(d, d, loss);
            d = aM1[r] - f1; loss = fmaf(d, d, loss);
        }
    }

#pragma unroll
    for (int o = 32; o > 0; o >>= 1) loss += __shfl_xor(loss, o, 64);
    if (lane == 0) atomicAdd(out, loss);
}

extern "C" void kernel_launch(void* const* d_in, const int* in_sizes, int n_in,
                              void* d_out, int out_size, void* d_ws, size_t ws_size,
                              hipStream_t stream) {
    const int*   pos_n   = (const int*)d_in[0];
    const int*   pos_m   = (const int*)d_in[1];
    const int*   pos_f   = (const int*)d_in[2];
    const float* nci_emb = (const float*)d_in[3];
    const float* fma_emb = (const float*)d_in[4];
    const float* n2f_mat = (const float*)d_in[5];
    const float* m2f_mat = (const float*)d_in[6];
    float* out = (float*)d_out;

    const int B = in_sizes[0];
    const int iters = B / (NBLOCKS * SPB);  // 1,048,576 -> 4

    const size_t TBL  = (size_t)NCI_ELEMS + (size_t)FMA_ELEMS;      // 16,000,000
    const size_t PERM = 3ull * (size_t)B * sizeof(int);             // 12,582,912
    const size_t CNTB = (size_t)NBUCKETS * CNT_STRIDE * sizeof(unsigned);

    if (ws_size >= TBL + PERM + CNTB && iters * NBLOCKS * SPB == B) {
        // ---- sorted fp8 path.
        unsigned char* nci8 = (unsigned char*)d_ws;
        unsigned char* fma8 = nci8 + NCI_ELEMS;      // 9,600,000 is 64B-aligned
        int* sn = (int*)(nci8 + TBL);                // 16,000,000 is 64B-aligned
        int* sm = sn + B;
        int* sf = sm + B;
        unsigned* cnt = (unsigned*)(sf + B);         // 28,582,912 is 64B-aligned

        convert_kernel<<<2048, 256, 0, stream>>>(
            (const float4*)nci_emb, (const float4*)fma_emb,
            (uint4*)nci8, (uint4*)fma8, out, cnt);
        hist_kernel<<<1024, 256, 0, stream>>>(pos_f, cnt, B);
        scan_kernel<<<1, 256, 0, stream>>>(cnt);
        scatter_kernel<<<(B + 255) / 256, 256, 0, stream>>>(
            pos_n, pos_m, pos_f, cnt, sn, sm, sf, B);
        ontomap_kernel_q<1><<<NBLOCKS, 256, 0, stream>>>(
            sn, sm, sf, nci8, fma8, n2f_mat, m2f_mat, out, iters);
    } else if (ws_size >= TBL) {
        // ---- unsorted fp8 path (R11).
        unsigned char* nci8 = (unsigned char*)d_ws;
        unsigned char* fma8 = nci8 + NCI_ELEMS;
        convert_kernel<<<2048, 256, 0, stream>>>(
            (const float4*)nci_emb, (const float4*)fma_emb,
            (uint4*)nci8, (uint4*)fma8, out, (unsigned*)nullptr);
        ontomap_kernel_q<0><<<NBLOCKS, 256, 0, stream>>>(
            pos_n, pos_m, pos_f, nci8, fma8, n2f_mat, m2f_mat, out, iters);
    } else {
        (void)hipMemsetAsync(out, 0, sizeof(float), stream);
        ontomap_kernel_f32<<<NBLOCKS, 256, 0, stream>>>(
            pos_n, pos_m, pos_f, nci_emb, fma_emb, n2f_mat, m2f_mat, out, iters);
    }
}

// Round 4
// 294.024 us; speedup vs baseline: 1.7677x; 1.0294x over previous
//
#include <hip/hip_runtime.h>
#include <hip/hip_fp16.h>

// Ontomap: loss = sum((n2f@n_e - f_e)^2) + sum((m2f@m_e - f_e)^2)
// B = 1,048,576, D = 64.
// Round 14: sort pipeline DROPPED (R13: scatter alone = 77us, 102MB of
// scattered 4B writes -> 8.5x write amplification; infra costs >> savings).
// Back to the R11 two-kernel structure. Single change vs R11:
// __launch_bounds__(256,6). R11's (256,4) capped residency at 16 waves/CU
// irrespective of grid size, so the R10->R11 "2x waves" test never actually
// doubled resident waves -- the latency-bound hypothesis is still live.
// (256,6) raises the VGPR cap to 85 (>= the 64 currently used: no spill
// possible) and residency to 24 waves/CU (+50% in-flight gather misses).

typedef _Float16 half8 __attribute__((ext_vector_type(8)));
typedef __fp16  fp16x2 __attribute__((ext_vector_type(2)));
typedef float floatx16 __attribute__((ext_vector_type(16)));

#define NBLOCKS 2048
#define SPB 128                 // samples per block-iteration: 4 waves * 32
#define NCI_ELEMS 9600000       // 150000 * 64
#define FMA_ELEMS 6400000       // 100000 * 64

__device__ inline half8 cvt8(float4 a, float4 b) {
    union { half8 h; fp16x2 h2[4]; } u;
    u.h2[0] = __builtin_amdgcn_cvt_pkrtz(a.x, a.y);
    u.h2[1] = __builtin_amdgcn_cvt_pkrtz(a.z, a.w);
    u.h2[2] = __builtin_amdgcn_cvt_pkrtz(b.x, b.y);
    u.h2[3] = __builtin_amdgcn_cvt_pkrtz(b.z, b.w);
    return u.h;
}

__device__ inline uint2 pack4(float4 v) {
    union { fp16x2 h2[2]; uint2 u; } p;
    p.h2[0] = __builtin_amdgcn_cvt_pkrtz(v.x, v.y);
    p.h2[1] = __builtin_amdgcn_cvt_pkrtz(v.z, v.w);
    return p.u;
}

// 8 fp32 -> 8 fp8-e4m3 bytes (ascending order).
__device__ inline uint2 pack8_fp8(float4 a, float4 b) {
    int lo = 0, hi = 0;
    lo = __builtin_amdgcn_cvt_pk_fp8_f32(a.x, a.y, lo, false);
    lo = __builtin_amdgcn_cvt_pk_fp8_f32(a.z, a.w, lo, true);
    hi = __builtin_amdgcn_cvt_pk_fp8_f32(b.x, b.y, hi, false);
    hi = __builtin_amdgcn_cvt_pk_fp8_f32(b.z, b.w, hi, true);
    uint2 r; r.x = (unsigned)lo; r.y = (unsigned)hi; return r;
}

__device__ inline long pack8_fp8_l(const float* p) {
    uint2 b = pack8_fp8(*(const float4*)p, *(const float4*)(p + 4));
    return (long)(((unsigned long)b.y << 32) | b.x);
}

// ---- streaming conversion: both tables -> fp8, into workspace.
// Also zeroes the loss accumulator (replaces the hipMemsetAsync dispatch).
__global__ __launch_bounds__(256) void convert_kernel(
    const float4* __restrict__ nci, const float4* __restrict__ fma,
    uint4* __restrict__ nci8, uint4* __restrict__ fma8, float* __restrict__ out)
{
    const int stride = gridDim.x * blockDim.x;
    const int tid = blockIdx.x * blockDim.x + threadIdx.x;
    if (tid == 0) out[0] = 0.0f;
    for (int i = tid; i < NCI_ELEMS / 16; i += stride) {
        uint2 lo = pack8_fp8(nci[4 * i],     nci[4 * i + 1]);
        uint2 hi = pack8_fp8(nci[4 * i + 2], nci[4 * i + 3]);
        nci8[i] = make_uint4(lo.x, lo.y, hi.x, hi.y);
    }
    for (int i = tid; i < FMA_ELEMS / 16; i += stride) {
        uint2 lo = pack8_fp8(fma[4 * i],     fma[4 * i + 1]);
        uint2 hi = pack8_fp8(fma[4 * i + 2], fma[4 * i + 3]);
        fma8[i] = make_uint4(lo.x, lo.y, hi.x, hi.y);
    }
}

// ---- main kernel: fp8 tables, K-remapped dwordx4 gathers, sequential tiles.
__global__ __launch_bounds__(256, 6) void ontomap_kernel_q(
    const int* __restrict__ pos_n, const int* __restrict__ pos_m,
    const int* __restrict__ pos_f,
    const unsigned char* __restrict__ nci8, const unsigned char* __restrict__ fma8,
    const float* __restrict__ n2f, const float* __restrict__ m2f,
    float* __restrict__ out, int iters)
{
    const int lane = threadIdx.x & 63;
    const int wave = threadIdx.x >> 6;
    const int l31  = lane & 31;
    const int hi   = lane >> 5;
    const int hoff = hi * 32;     // this lane's contiguous 32-byte half-row

    // B fragments under the K-remap k = hoff + t*8 + j:
    // MFMA step t, B slot (hi,j) = M[n][hoff + t*8 + j], n = nt*32 + l31.
    long Bn[2][4], Bm[2][4];
#pragma unroll
    for (int nt = 0; nt < 2; ++nt) {
#pragma unroll
        for (int t = 0; t < 4; ++t) {
            Bn[nt][t] = pack8_fp8_l(n2f + (nt * 32 + l31) * 64 + hoff + t * 8);
            Bm[nt][t] = pack8_fp8_l(m2f + (nt * 32 + l31) * 64 + hoff + t * 8);
        }
    }

    // -I fragments (fp8 0xB8 = -1.0 e4m3). Under the remap, tile0's diagonal
    // lives in hi=0 slots, tile1's in hi=1 slots: step t has -1 at byte
    // j = l31 - t*8 when 0 <= j < 8.  (Verified correct in round 9.)
    long If0[4], If1[4];
#pragma unroll
    for (int t = 0; t < 4; ++t) {
        const unsigned j = (unsigned)(l31 - t * 8);
        const long pat = (j < 8) ? (long)(0xB8ULL << (8 * j)) : 0L;
        If0[t] = hi ? 0L : pat;
        If1[t] = hi ? pat : 0L;
    }

    float l0 = 0.0f, l1 = 0.0f, l2 = 0.0f, l3 = 0.0f;

    int in_, im_, if_;
    {
        int s = blockIdx.x * SPB + wave * 32 + l31;
        in_ = pos_n[s]; im_ = pos_m[s]; if_ = pos_f[s];
    }

#pragma unroll 1
    for (int it = 0; it < iters; ++it) {
        const int in0 = in_, im0 = im_, if0 = if_;
        if (it + 1 < iters) {
            int s = ((it + 1) * NBLOCKS + blockIdx.x) * SPB + wave * 32 + l31;
            in_ = pos_n[s]; im_ = pos_m[s]; if_ = pos_f[s];
        }

        // ---- 6 independent dwordx4 gathers (32 contiguous B per lane).
        // Order: An, Ff, Am -- so Am is still in flight during n-tiles.
        const unsigned char* pn = nci8 + (long)in0 * 64 + hoff;
        const unsigned char* pf = fma8 + (long)if0 * 64 + hoff;
        const unsigned char* pm = nci8 + (long)im0 * 64 + hoff;

        ulonglong2 n01 = *(const ulonglong2*)pn;
        ulonglong2 n23 = *(const ulonglong2*)(pn + 16);
        ulonglong2 f01 = *(const ulonglong2*)pf;
        ulonglong2 f23 = *(const ulonglong2*)(pf + 16);
        ulonglong2 m01 = *(const ulonglong2*)pm;
        ulonglong2 m23 = *(const ulonglong2*)(pm + 16);

        const long An[4] = {(long)n01.x, (long)n01.y, (long)n23.x, (long)n23.y};
        const long Ff[4] = {(long)f01.x, (long)f01.y, (long)f23.x, (long)f23.y};
        const long Am[4] = {(long)m01.x, (long)m01.y, (long)m23.x, (long)m23.y};

        // ---- sequential tiles: one 16-reg accumulator live at a time.
        {   // n-loss, tile 0 (dims 0..31)
            floatx16 a{};
#pragma unroll
            for (int t = 0; t < 4; ++t)
                a = __builtin_amdgcn_mfma_f32_32x32x16_fp8_fp8(An[t], Bn[0][t], a, 0, 0, 0);
#pragma unroll
            for (int t = 0; t < 4; ++t)
                a = __builtin_amdgcn_mfma_f32_32x32x16_fp8_fp8(Ff[t], If0[t], a, 0, 0, 0);
#pragma unroll
            for (int r = 0; r < 16; r += 4) {
                l0 = fmaf(a[r],     a[r],     l0);
                l1 = fmaf(a[r + 1], a[r + 1], l1);
                l2 = fmaf(a[r + 2], a[r + 2], l2);
                l3 = fmaf(a[r + 3], a[r + 3], l3);
            }
        }
        {   // n-loss, tile 1 (dims 32..63)
            floatx16 a{};
#pragma unroll
            for (int t = 0; t < 4; ++t)
                a = __builtin_amdgcn_mfma_f32_32x32x16_fp8_fp8(An[t], Bn[1][t], a, 0, 0, 0);
#pragma unroll
            for (int t = 0; t < 4; ++t)
                a = __builtin_amdgcn_mfma_f32_32x32x16_fp8_fp8(Ff[t], If1[t], a, 0, 0, 0);
#pragma unroll
            for (int r = 0; r < 16; r += 4) {
                l0 = fmaf(a[r],     a[r],     l0);
                l1 = fmaf(a[r + 1], a[r + 1], l1);
                l2 = fmaf(a[r + 2], a[r + 2], l2);
                l3 = fmaf(a[r + 3], a[r + 3], l3);
            }
        }
        {   // m-loss, tile 0
            floatx16 a{};
#pragma unroll
            for (int t = 0; t < 4; ++t)
                a = __builtin_amdgcn_mfma_f32_32x32x16_fp8_fp8(Am[t], Bm[0][t], a, 0, 0, 0);
#pragma unroll
            for (int t = 0; t < 4; ++t)
                a = __builtin_amdgcn_mfma_f32_32x32x16_fp8_fp8(Ff[t], If0[t], a, 0, 0, 0);
#pragma unroll
            for (int r = 0; r < 16; r += 4) {
                l0 = fmaf(a[r],     a[r],     l0);
                l1 = fmaf(a[r + 1], a[r + 1], l1);
                l2 = fmaf(a[r + 2], a[r + 2], l2);
                l3 = fmaf(a[r + 3], a[r + 3], l3);
            }
        }
        {   // m-loss, tile 1
            floatx16 a{};
#pragma unroll
            for (int t = 0; t < 4; ++t)
                a = __builtin_amdgcn_mfma_f32_32x32x16_fp8_fp8(Am[t], Bm[1][t], a, 0, 0, 0);
#pragma unroll
            for (int t = 0; t < 4; ++t)
                a = __builtin_amdgcn_mfma_f32_32x32x16_fp8_fp8(Ff[t], If1[t], a, 0, 0, 0);
#pragma unroll
            for (int r = 0; r < 16; r += 4) {
                l0 = fmaf(a[r],     a[r],     l0);
                l1 = fmaf(a[r + 1], a[r + 1], l1);
                l2 = fmaf(a[r + 2], a[r + 2], l2);
                l3 = fmaf(a[r + 3], a[r + 3], l3);
            }
        }
    }

    float loss = (l0 + l1) + (l2 + l3);
#pragma unroll
    for (int o = 32; o > 0; o >>= 1) loss += __shfl_xor(loss, o, 64);

    // block-level reduction: 1 atomic per block instead of 4.
    __shared__ float red[4];
    if (lane == 0) red[wave] = loss;
    __syncthreads();
    if (threadIdx.x == 0)
        atomicAdd(out, (red[0] + red[1]) + (red[2] + red[3]));
}

// ---- fallback: fp32 tables with LDS staging (round-4 style), if ws too small.
#define ROW_BYTES 144
__global__ __launch_bounds__(256, 2) void ontomap_kernel_f32(
    const int* __restrict__ pos_n, const int* __restrict__ pos_m,
    const int* __restrict__ pos_f,
    const float* __restrict__ nci, const float* __restrict__ fma_emb,
    const float* __restrict__ n2f, const float* __restrict__ m2f,
    float* __restrict__ out, int iters)
{
    __shared__ char lds[4 * 2 * 32 * ROW_BYTES];

    const int lane = threadIdx.x & 63;
    const int wave = threadIdx.x >> 6;
    const int l31  = lane & 31;
    const int hi   = lane >> 5;
    const int kbase = hi * 8;
    const int srow   = lane >> 4;
    const int schunk = lane & 15;

    char* const nbase = lds + wave * (2 * 32 * ROW_BYTES);
    char* const mbase = nbase + 32 * ROW_BYTES;

    half8 Bn[2][4], Bm[2][4];
#pragma unroll
    for (int nt = 0; nt < 2; ++nt) {
#pragma unroll
        for (int t = 0; t < 4; ++t) {
            const float* p = n2f + (nt * 32 + l31) * 64 + t * 16 + kbase;
            Bn[nt][t] = cvt8(*(const float4*)p, *(const float4*)(p + 4));
            const float* q = m2f + (nt * 32 + l31) * 64 + t * 16 + kbase;
            Bm[nt][t] = cvt8(*(const float4*)q, *(const float4*)(q + 4));
        }
    }

    float loss = 0.0f;
    int in_, im_, if_;
    {
        int s = blockIdx.x * SPB + wave * 32 + l31;
        in_ = pos_n[s]; im_ = pos_m[s]; if_ = pos_f[s];
    }

#pragma unroll 1
    for (int it = 0; it < iters; ++it) {
        const int in0 = in_, im0 = im_, if0 = if_;
        if (it + 1 < iters) {
            int s = ((it + 1) * NBLOCKS + blockIdx.x) * SPB + wave * 32 + l31;
            in_ = pos_n[s]; im_ = pos_m[s]; if_ = pos_f[s];
        }

#pragma unroll
        for (int i = 0; i < 8; ++i) {
            const int rl = i * 4 + srow;
            const int rn = __shfl(in0, rl, 64);
            float4 v = ((const float4*)(nci + (long)rn * 64))[schunk];
            *(uint2*)(nbase + rl * ROW_BYTES + schunk * 8) = pack4(v);
            const int rm = __shfl(im0, rl, 64);
            float4 w = ((const float4*)(nci + (long)rm * 64))[schunk];
            *(uint2*)(mbase + rl * ROW_BYTES + schunk * 8) = pack4(w);
        }
        asm volatile("" ::: "memory");

        floatx16 aN0{}, aN1{}, aM0{}, aM1{};
#pragma unroll
        for (int t = 0; t < 4; ++t) {
            half8 aF = *(const half8*)(nbase + l31 * ROW_BYTES + t * 32 + hi * 16);
            aN0 = __builtin_amdgcn_mfma_f32_32x32x16_f16(aF, Bn[0][t], aN0, 0, 0, 0);
            aN1 = __builtin_amdgcn_mfma_f32_32x32x16_f16(aF, Bn[1][t], aN1, 0, 0, 0);
            half8 bF = *(const half8*)(mbase + l31 * ROW_BYTES + t * 32 + hi * 16);
            aM0 = __builtin_amdgcn_mfma_f32_32x32x16_f16(bF, Bm[0][t], aM0, 0, 0, 0);
            aM1 = __builtin_amdgcn_mfma_f32_32x32x16_f16(bF, Bm[1][t], aM1, 0, 0, 0);
        }

#pragma unroll
        for (int r = 0; r < 16; ++r) {
            const int mrow = (r & 3) + 8 * (r >> 2) + 4 * hi;
            const int fid  = __shfl(if0, mrow, 64);
            const float* pf = fma_emb + (long)fid * 64 + l31;
            const float f0 = pf[0];
            const float f1 = pf[32];
            float d;
            d = aN0[r] - f0; loss = fmaf(d, d, loss);
            d = aM0[r] - f0; loss = fmaf(d, d, loss);
            d = aN1[r] - f1; loss = fmaf(d, d, loss);
            d = aM1[r] - f1; loss = fmaf(d, d, loss);
        }
    }

#pragma unroll
    for (int o = 32; o > 0; o >>= 1) loss += __shfl_xor(loss, o, 64);
    if (lane == 0) atomicAdd(out, loss);
}

extern "C" void kernel_launch(void* const* d_in, const int* in_sizes, int n_in,
                              void* d_out, int out_size, void* d_ws, size_t ws_size,
                              hipStream_t stream) {
    const int*   pos_n   = (const int*)d_in[0];
    const int*   pos_m   = (const int*)d_in[1];
    const int*   pos_f   = (const int*)d_in[2];
    const float* nci_emb = (const float*)d_in[3];
    const float* fma_emb = (const float*)d_in[4];
    const float* n2f_mat = (const float*)d_in[5];
    const float* m2f_mat = (const float*)d_in[6];
    float* out = (float*)d_out;

    const int B = in_sizes[0];
    const int iters = B / (NBLOCKS * SPB);  // 1,048,576 -> 4

    const size_t need = (size_t)NCI_ELEMS + (size_t)FMA_ELEMS;  // 16 MB
    if (ws_size >= need) {
        unsigned char* nci8 = (unsigned char*)d_ws;
        unsigned char* fma8 = nci8 + NCI_ELEMS;   // 9,600,000 is 64B-aligned
        convert_kernel<<<2048, 256, 0, stream>>>(
            (const float4*)nci_emb, (const float4*)fma_emb,
            (uint4*)nci8, (uint4*)fma8, out);
        ontomap_kernel_q<<<NBLOCKS, 256, 0, stream>>>(
            pos_n, pos_m, pos_f, nci8, fma8, n2f_mat, m2f_mat, out, iters);
    } else {
        (void)hipMemsetAsync(out, 0, sizeof(float), stream);
        ontomap_kernel_f32<<<NBLOCKS, 256, 0, stream>>>(
            pos_n, pos_m, pos_f, nci_emb, fma_emb, n2f_mat, m2f_mat, out, iters);
    }
}

// Round 5
// 201.060 us; speedup vs baseline: 2.5850x; 1.4624x over previous
//
#include <hip/hip_runtime.h>
#include <hip/hip_fp16.h>

// Ontomap: loss = sum((n2f@n_e - f_e)^2) + sum((m2f@m_e - f_e)^2)
// B = 1,048,576, D = 64.
// Round 15: grid granularity. R14's launch_bounds(256,6) forced VGPR=40 ->
// spill (2nd arg shrinks the allocator budget; >=6 always spills this
// kernel). Codegen pinned back to (256,4)/VGPR=64 (known good, R11).
// Single change vs R11: NBLOCKS 2048 -> 4096 (iters 4 -> 2). R11's grid was
// exactly residency capacity (256 CU x 8 blocks) -> zero backfill slack;
// measured occupancy 34% = straggler tail. 2x oversubscription lets freed
// slots backfill and halves per-straggler cost.

typedef _Float16 half8 __attribute__((ext_vector_type(8)));
typedef __fp16  fp16x2 __attribute__((ext_vector_type(2)));
typedef float floatx16 __attribute__((ext_vector_type(16)));

#define NBLOCKS 4096
#define SPB 128                 // samples per block-iteration: 4 waves * 32
#define NCI_ELEMS 9600000       // 150000 * 64
#define FMA_ELEMS 6400000       // 100000 * 64

__device__ inline half8 cvt8(float4 a, float4 b) {
    union { half8 h; fp16x2 h2[4]; } u;
    u.h2[0] = __builtin_amdgcn_cvt_pkrtz(a.x, a.y);
    u.h2[1] = __builtin_amdgcn_cvt_pkrtz(a.z, a.w);
    u.h2[2] = __builtin_amdgcn_cvt_pkrtz(b.x, b.y);
    u.h2[3] = __builtin_amdgcn_cvt_pkrtz(b.z, b.w);
    return u.h;
}

__device__ inline uint2 pack4(float4 v) {
    union { fp16x2 h2[2]; uint2 u; } p;
    p.h2[0] = __builtin_amdgcn_cvt_pkrtz(v.x, v.y);
    p.h2[1] = __builtin_amdgcn_cvt_pkrtz(v.z, v.w);
    return p.u;
}

// 8 fp32 -> 8 fp8-e4m3 bytes (ascending order).
__device__ inline uint2 pack8_fp8(float4 a, float4 b) {
    int lo = 0, hi = 0;
    lo = __builtin_amdgcn_cvt_pk_fp8_f32(a.x, a.y, lo, false);
    lo = __builtin_amdgcn_cvt_pk_fp8_f32(a.z, a.w, lo, true);
    hi = __builtin_amdgcn_cvt_pk_fp8_f32(b.x, b.y, hi, false);
    hi = __builtin_amdgcn_cvt_pk_fp8_f32(b.z, b.w, hi, true);
    uint2 r; r.x = (unsigned)lo; r.y = (unsigned)hi; return r;
}

__device__ inline long pack8_fp8_l(const float* p) {
    uint2 b = pack8_fp8(*(const float4*)p, *(const float4*)(p + 4));
    return (long)(((unsigned long)b.y << 32) | b.x);
}

// ---- streaming conversion: both tables -> fp8, into workspace.
// Also zeroes the loss accumulator (replaces the hipMemsetAsync dispatch).
__global__ __launch_bounds__(256) void convert_kernel(
    const float4* __restrict__ nci, const float4* __restrict__ fma,
    uint4* __restrict__ nci8, uint4* __restrict__ fma8, float* __restrict__ out)
{
    const int stride = gridDim.x * blockDim.x;
    const int tid = blockIdx.x * blockDim.x + threadIdx.x;
    if (tid == 0) out[0] = 0.0f;
    for (int i = tid; i < NCI_ELEMS / 16; i += stride) {
        uint2 lo = pack8_fp8(nci[4 * i],     nci[4 * i + 1]);
        uint2 hi = pack8_fp8(nci[4 * i + 2], nci[4 * i + 3]);
        nci8[i] = make_uint4(lo.x, lo.y, hi.x, hi.y);
    }
    for (int i = tid; i < FMA_ELEMS / 16; i += stride) {
        uint2 lo = pack8_fp8(fma[4 * i],     fma[4 * i + 1]);
        uint2 hi = pack8_fp8(fma[4 * i + 2], fma[4 * i + 3]);
        fma8[i] = make_uint4(lo.x, lo.y, hi.x, hi.y);
    }
}

// ---- main kernel: fp8 tables, K-remapped dwordx4 gathers, sequential tiles.
__global__ __launch_bounds__(256, 4) void ontomap_kernel_q(
    const int* __restrict__ pos_n, const int* __restrict__ pos_m,
    const int* __restrict__ pos_f,
    const unsigned char* __restrict__ nci8, const unsigned char* __restrict__ fma8,
    const float* __restrict__ n2f, const float* __restrict__ m2f,
    float* __restrict__ out, int iters)
{
    const int lane = threadIdx.x & 63;
    const int wave = threadIdx.x >> 6;
    const int l31  = lane & 31;
    const int hi   = lane >> 5;
    const int hoff = hi * 32;     // this lane's contiguous 32-byte half-row

    // B fragments under the K-remap k = hoff + t*8 + j:
    // MFMA step t, B slot (hi,j) = M[n][hoff + t*8 + j], n = nt*32 + l31.
    long Bn[2][4], Bm[2][4];
#pragma unroll
    for (int nt = 0; nt < 2; ++nt) {
#pragma unroll
        for (int t = 0; t < 4; ++t) {
            Bn[nt][t] = pack8_fp8_l(n2f + (nt * 32 + l31) * 64 + hoff + t * 8);
            Bm[nt][t] = pack8_fp8_l(m2f + (nt * 32 + l31) * 64 + hoff + t * 8);
        }
    }

    // -I fragments (fp8 0xB8 = -1.0 e4m3). Under the remap, tile0's diagonal
    // lives in hi=0 slots, tile1's in hi=1 slots: step t has -1 at byte
    // j = l31 - t*8 when 0 <= j < 8.  (Verified correct in round 9.)
    long If0[4], If1[4];
#pragma unroll
    for (int t = 0; t < 4; ++t) {
        const unsigned j = (unsigned)(l31 - t * 8);
        const long pat = (j < 8) ? (long)(0xB8ULL << (8 * j)) : 0L;
        If0[t] = hi ? 0L : pat;
        If1[t] = hi ? pat : 0L;
    }

    float l0 = 0.0f, l1 = 0.0f, l2 = 0.0f, l3 = 0.0f;

    int in_, im_, if_;
    {
        int s = blockIdx.x * SPB + wave * 32 + l31;
        in_ = pos_n[s]; im_ = pos_m[s]; if_ = pos_f[s];
    }

#pragma unroll 1
    for (int it = 0; it < iters; ++it) {
        const int in0 = in_, im0 = im_, if0 = if_;
        if (it + 1 < iters) {
            int s = ((it + 1) * NBLOCKS + blockIdx.x) * SPB + wave * 32 + l31;
            in_ = pos_n[s]; im_ = pos_m[s]; if_ = pos_f[s];
        }

        // ---- 6 independent dwordx4 gathers (32 contiguous B per lane).
        // Order: An, Ff, Am -- so Am is still in flight during n-tiles.
        const unsigned char* pn = nci8 + (long)in0 * 64 + hoff;
        const unsigned char* pf = fma8 + (long)if0 * 64 + hoff;
        const unsigned char* pm = nci8 + (long)im0 * 64 + hoff;

        ulonglong2 n01 = *(const ulonglong2*)pn;
        ulonglong2 n23 = *(const ulonglong2*)(pn + 16);
        ulonglong2 f01 = *(const ulonglong2*)pf;
        ulonglong2 f23 = *(const ulonglong2*)(pf + 16);
        ulonglong2 m01 = *(const ulonglong2*)pm;
        ulonglong2 m23 = *(const ulonglong2*)(pm + 16);

        const long An[4] = {(long)n01.x, (long)n01.y, (long)n23.x, (long)n23.y};
        const long Ff[4] = {(long)f01.x, (long)f01.y, (long)f23.x, (long)f23.y};
        const long Am[4] = {(long)m01.x, (long)m01.y, (long)m23.x, (long)m23.y};

        // ---- sequential tiles: one 16-reg accumulator live at a time.
        {   // n-loss, tile 0 (dims 0..31)
            floatx16 a{};
#pragma unroll
            for (int t = 0; t < 4; ++t)
                a = __builtin_amdgcn_mfma_f32_32x32x16_fp8_fp8(An[t], Bn[0][t], a, 0, 0, 0);
#pragma unroll
            for (int t = 0; t < 4; ++t)
                a = __builtin_amdgcn_mfma_f32_32x32x16_fp8_fp8(Ff[t], If0[t], a, 0, 0, 0);
#pragma unroll
            for (int r = 0; r < 16; r += 4) {
                l0 = fmaf(a[r],     a[r],     l0);
                l1 = fmaf(a[r + 1], a[r + 1], l1);
                l2 = fmaf(a[r + 2], a[r + 2], l2);
                l3 = fmaf(a[r + 3], a[r + 3], l3);
            }
        }
        {   // n-loss, tile 1 (dims 32..63)
            floatx16 a{};
#pragma unroll
            for (int t = 0; t < 4; ++t)
                a = __builtin_amdgcn_mfma_f32_32x32x16_fp8_fp8(An[t], Bn[1][t], a, 0, 0, 0);
#pragma unroll
            for (int t = 0; t < 4; ++t)
                a = __builtin_amdgcn_mfma_f32_32x32x16_fp8_fp8(Ff[t], If1[t], a, 0, 0, 0);
#pragma unroll
            for (int r = 0; r < 16; r += 4) {
                l0 = fmaf(a[r],     a[r],     l0);
                l1 = fmaf(a[r + 1], a[r + 1], l1);
                l2 = fmaf(a[r + 2], a[r + 2], l2);
                l3 = fmaf(a[r + 3], a[r + 3], l3);
            }
        }
        {   // m-loss, tile 0
            floatx16 a{};
#pragma unroll
            for (int t = 0; t < 4; ++t)
                a = __builtin_amdgcn_mfma_f32_32x32x16_fp8_fp8(Am[t], Bm[0][t], a, 0, 0, 0);
#pragma unroll
            for (int t = 0; t < 4; ++t)
                a = __builtin_amdgcn_mfma_f32_32x32x16_fp8_fp8(Ff[t], If0[t], a, 0, 0, 0);
#pragma unroll
            for (int r = 0; r < 16; r += 4) {
                l0 = fmaf(a[r],     a[r],     l0);
                l1 = fmaf(a[r + 1], a[r + 1], l1);
                l2 = fmaf(a[r + 2], a[r + 2], l2);
                l3 = fmaf(a[r + 3], a[r + 3], l3);
            }
        }
        {   // m-loss, tile 1
            floatx16 a{};
#pragma unroll
            for (int t = 0; t < 4; ++t)
                a = __builtin_amdgcn_mfma_f32_32x32x16_fp8_fp8(Am[t], Bm[1][t], a, 0, 0, 0);
#pragma unroll
            for (int t = 0; t < 4; ++t)
                a = __builtin_amdgcn_mfma_f32_32x32x16_fp8_fp8(Ff[t], If1[t], a, 0, 0, 0);
#pragma unroll
            for (int r = 0; r < 16; r += 4) {
                l0 = fmaf(a[r],     a[r],     l0);
                l1 = fmaf(a[r + 1], a[r + 1], l1);
                l2 = fmaf(a[r + 2], a[r + 2], l2);
                l3 = fmaf(a[r + 3], a[r + 3], l3);
            }
        }
    }

    float loss = (l0 + l1) + (l2 + l3);
#pragma unroll
    for (int o = 32; o > 0; o >>= 1) loss += __shfl_xor(loss, o, 64);

    // block-level reduction: 1 atomic per block instead of 4.
    __shared__ float red[4];
    if (lane == 0) red[wave] = loss;
    __syncthreads();
    if (threadIdx.x == 0)
        atomicAdd(out, (red[0] + red[1]) + (red[2] + red[3]));
}

// ---- fallback: fp32 tables with LDS staging (round-4 style), if ws too small.
#define ROW_BYTES 144
__global__ __launch_bounds__(256, 2) void ontomap_kernel_f32(
    const int* __restrict__ pos_n, const int* __restrict__ pos_m,
    const int* __restrict__ pos_f,
    const float* __restrict__ nci, const float* __restrict__ fma_emb,
    const float* __restrict__ n2f, const float* __restrict__ m2f,
    float* __restrict__ out, int iters)
{
    __shared__ char lds[4 * 2 * 32 * ROW_BYTES];

    const int lane = threadIdx.x & 63;
    const int wave = threadIdx.x >> 6;
    const int l31  = lane & 31;
    const int hi   = lane >> 5;
    const int kbase = hi * 8;
    const int srow   = lane >> 4;
    const int schunk = lane & 15;

    char* const nbase = lds + wave * (2 * 32 * ROW_BYTES);
    char* const mbase = nbase + 32 * ROW_BYTES;

    half8 Bn[2][4], Bm[2][4];
#pragma unroll
    for (int nt = 0; nt < 2; ++nt) {
#pragma unroll
        for (int t = 0; t < 4; ++t) {
            const float* p = n2f + (nt * 32 + l31) * 64 + t * 16 + kbase;
            Bn[nt][t] = cvt8(*(const float4*)p, *(const float4*)(p + 4));
            const float* q = m2f + (nt * 32 + l31) * 64 + t * 16 + kbase;
            Bm[nt][t] = cvt8(*(const float4*)q, *(const float4*)(q + 4));
        }
    }

    float loss = 0.0f;
    int in_, im_, if_;
    {
        int s = blockIdx.x * SPB + wave * 32 + l31;
        in_ = pos_n[s]; im_ = pos_m[s]; if_ = pos_f[s];
    }

#pragma unroll 1
    for (int it = 0; it < iters; ++it) {
        const int in0 = in_, im0 = im_, if0 = if_;
        if (it + 1 < iters) {
            int s = ((it + 1) * NBLOCKS + blockIdx.x) * SPB + wave * 32 + l31;
            in_ = pos_n[s]; im_ = pos_m[s]; if_ = pos_f[s];
        }

#pragma unroll
        for (int i = 0; i < 8; ++i) {
            const int rl = i * 4 + srow;
            const int rn = __shfl(in0, rl, 64);
            float4 v = ((const float4*)(nci + (long)rn * 64))[schunk];
            *(uint2*)(nbase + rl * ROW_BYTES + schunk * 8) = pack4(v);
            const int rm = __shfl(im0, rl, 64);
            float4 w = ((const float4*)(nci + (long)rm * 64))[schunk];
            *(uint2*)(mbase + rl * ROW_BYTES + schunk * 8) = pack4(w);
        }
        asm volatile("" ::: "memory");

        floatx16 aN0{}, aN1{}, aM0{}, aM1{};
#pragma unroll
        for (int t = 0; t < 4; ++t) {
            half8 aF = *(const half8*)(nbase + l31 * ROW_BYTES + t * 32 + hi * 16);
            aN0 = __builtin_amdgcn_mfma_f32_32x32x16_f16(aF, Bn[0][t], aN0, 0, 0, 0);
            aN1 = __builtin_amdgcn_mfma_f32_32x32x16_f16(aF, Bn[1][t], aN1, 0, 0, 0);
            half8 bF = *(const half8*)(mbase + l31 * ROW_BYTES + t * 32 + hi * 16);
            aM0 = __builtin_amdgcn_mfma_f32_32x32x16_f16(bF, Bm[0][t], aM0, 0, 0, 0);
            aM1 = __builtin_amdgcn_mfma_f32_32x32x16_f16(bF, Bm[1][t], aM1, 0, 0, 0);
        }

#pragma unroll
        for (int r = 0; r < 16; ++r) {
            const int mrow = (r & 3) + 8 * (r >> 2) + 4 * hi;
            const int fid  = __shfl(if0, mrow, 64);
            const float* pf = fma_emb + (long)fid * 64 + l31;
            const float f0 = pf[0];
            const float f1 = pf[32];
            float d;
            d = aN0[r] - f0; loss = fmaf(d, d, loss);
            d = aM0[r] - f0; loss = fmaf(d, d, loss);
            d = aN1[r] - f1; loss = fmaf(d, d, loss);
            d = aM1[r] - f1; loss = fmaf(d, d, loss);
        }
    }

#pragma unroll
    for (int o = 32; o > 0; o >>= 1) loss += __shfl_xor(loss, o, 64);
    if (lane == 0) atomicAdd(out, loss);
}

extern "C" void kernel_launch(void* const* d_in, const int* in_sizes, int n_in,
                              void* d_out, int out_size, void* d_ws, size_t ws_size,
                              hipStream_t stream) {
    const int*   pos_n   = (const int*)d_in[0];
    const int*   pos_m   = (const int*)d_in[1];
    const int*   pos_f   = (const int*)d_in[2];
    const float* nci_emb = (const float*)d_in[3];
    const float* fma_emb = (const float*)d_in[4];
    const float* n2f_mat = (const float*)d_in[5];
    const float* m2f_mat = (const float*)d_in[6];
    float* out = (float*)d_out;

    const int B = in_sizes[0];
    const int iters = B / (NBLOCKS * SPB);  // 1,048,576 -> 2

    const size_t need = (size_t)NCI_ELEMS + (size_t)FMA_ELEMS;  // 16 MB
    if (ws_size >= need) {
        unsigned char* nci8 = (unsigned char*)d_ws;
        unsigned char* fma8 = nci8 + NCI_ELEMS;   // 9,600,000 is 64B-aligned
        convert_kernel<<<2048, 256, 0, stream>>>(
            (const float4*)nci_emb, (const float4*)fma_emb,
            (uint4*)nci8, (uint4*)fma8, out);
        ontomap_kernel_q<<<NBLOCKS, 256, 0, stream>>>(
            pos_n, pos_m, pos_f, nci8, fma8, n2f_mat, m2f_mat, out, iters);
    } else {
        (void)hipMemsetAsync(out, 0, sizeof(float), stream);
        ontomap_kernel_f32<<<NBLOCKS, 256, 0, stream>>>(
            pos_n, pos_m, pos_f, nci_emb, fma_emb, n2f_mat, m2f_mat, out, iters);
    }
}

// Round 6
// 158.252 us; speedup vs baseline: 3.2843x; 1.2705x over previous
//
#include <hip/hip_runtime.h>
#include <hip/hip_fp16.h>

// Ontomap: loss = sum((n2f@n_e - f_e)^2) + sum((m2f@m_e - f_e)^2)
// B = 1,048,576, D = 64.
// Round 16: prologue hoist. R15 (4096 blocks) showed the per-block prologue
// (16x pack8_fp8_l = 32 float4 loads + 64 pack ops per thread) costs ~14us
// per 2048 blocks -- it regressed 71->99us when doubled. Revert to the best
// config (2048 blocks, iters=4, launch_bounds(256,4)/VGPR=64) and move the
// B-fragment packing into convert_kernel (done once by one wave, 8KB in ws).
// Main-kernel prologue is now 16 coalesced L2-hit dwordx2 loads per thread.
// Numerics bitwise-identical (same pack8_fp8_l results, same order).

typedef _Float16 half8 __attribute__((ext_vector_type(8)));
typedef __fp16  fp16x2 __attribute__((ext_vector_type(2)));
typedef float floatx16 __attribute__((ext_vector_type(16)));

#define NBLOCKS 2048
#define SPB 128                 // samples per block-iteration: 4 waves * 32
#define NCI_ELEMS 9600000       // 150000 * 64
#define FMA_ELEMS 6400000       // 100000 * 64
#define FRAG_LONGS 512          // 2 matrices * 8 frags * 64 lanes

__device__ inline half8 cvt8(float4 a, float4 b) {
    union { half8 h; fp16x2 h2[4]; } u;
    u.h2[0] = __builtin_amdgcn_cvt_pkrtz(a.x, a.y);
    u.h2[1] = __builtin_amdgcn_cvt_pkrtz(a.z, a.w);
    u.h2[2] = __builtin_amdgcn_cvt_pkrtz(b.x, b.y);
    u.h2[3] = __builtin_amdgcn_cvt_pkrtz(b.z, b.w);
    return u.h;
}

__device__ inline uint2 pack4(float4 v) {
    union { fp16x2 h2[2]; uint2 u; } p;
    p.h2[0] = __builtin_amdgcn_cvt_pkrtz(v.x, v.y);
    p.h2[1] = __builtin_amdgcn_cvt_pkrtz(v.z, v.w);
    return p.u;
}

// 8 fp32 -> 8 fp8-e4m3 bytes (ascending order).
__device__ inline uint2 pack8_fp8(float4 a, float4 b) {
    int lo = 0, hi = 0;
    lo = __builtin_amdgcn_cvt_pk_fp8_f32(a.x, a.y, lo, false);
    lo = __builtin_amdgcn_cvt_pk_fp8_f32(a.z, a.w, lo, true);
    hi = __builtin_amdgcn_cvt_pk_fp8_f32(b.x, b.y, hi, false);
    hi = __builtin_amdgcn_cvt_pk_fp8_f32(b.z, b.w, hi, true);
    uint2 r; r.x = (unsigned)lo; r.y = (unsigned)hi; return r;
}

__device__ inline long pack8_fp8_l(const float* p) {
    uint2 b = pack8_fp8(*(const float4*)p, *(const float4*)(p + 4));
    return (long)(((unsigned long)b.y << 32) | b.x);
}

// ---- streaming conversion: both tables -> fp8, into workspace.
// Also zeroes the loss accumulator and precomputes the per-lane packed
// B-fragments for both matrices (frag[(nt*4+t)*64 + lane], 8KB total).
__global__ __launch_bounds__(256) void convert_kernel(
    const float4* __restrict__ nci, const float4* __restrict__ fma,
    uint4* __restrict__ nci8, uint4* __restrict__ fma8, float* __restrict__ out,
    const float* __restrict__ n2f, const float* __restrict__ m2f,
    long* __restrict__ fragN, long* __restrict__ fragM)
{
    const int stride = gridDim.x * blockDim.x;
    const int tid = blockIdx.x * blockDim.x + threadIdx.x;
    if (tid == 0) out[0] = 0.0f;
    if (blockIdx.x == 0 && threadIdx.x < 64) {
        const int lane = threadIdx.x;
        const int l31 = lane & 31;
        const int hoff = (lane >> 5) * 32;
#pragma unroll
        for (int nt = 0; nt < 2; ++nt) {
#pragma unroll
            for (int t = 0; t < 4; ++t) {
                fragN[(nt * 4 + t) * 64 + lane] =
                    pack8_fp8_l(n2f + (nt * 32 + l31) * 64 + hoff + t * 8);
                fragM[(nt * 4 + t) * 64 + lane] =
                    pack8_fp8_l(m2f + (nt * 32 + l31) * 64 + hoff + t * 8);
            }
        }
    }
    for (int i = tid; i < NCI_ELEMS / 16; i += stride) {
        uint2 lo = pack8_fp8(nci[4 * i],     nci[4 * i + 1]);
        uint2 hi = pack8_fp8(nci[4 * i + 2], nci[4 * i + 3]);
        nci8[i] = make_uint4(lo.x, lo.y, hi.x, hi.y);
    }
    for (int i = tid; i < FMA_ELEMS / 16; i += stride) {
        uint2 lo = pack8_fp8(fma[4 * i],     fma[4 * i + 1]);
        uint2 hi = pack8_fp8(fma[4 * i + 2], fma[4 * i + 3]);
        fma8[i] = make_uint4(lo.x, lo.y, hi.x, hi.y);
    }
}

// ---- main kernel: fp8 tables, K-remapped dwordx4 gathers, sequential tiles.
__global__ __launch_bounds__(256, 4) void ontomap_kernel_q(
    const int* __restrict__ pos_n, const int* __restrict__ pos_m,
    const int* __restrict__ pos_f,
    const unsigned char* __restrict__ nci8, const unsigned char* __restrict__ fma8,
    const long* __restrict__ fragN, const long* __restrict__ fragM,
    float* __restrict__ out, int iters)
{
    const int lane = threadIdx.x & 63;
    const int wave = threadIdx.x >> 6;
    const int l31  = lane & 31;
    const int hi   = lane >> 5;
    const int hoff = hi * 32;     // this lane's contiguous 32-byte half-row

    // B fragments (precomputed in convert_kernel): 16 coalesced L2-hit loads.
    long Bn[2][4], Bm[2][4];
#pragma unroll
    for (int nt = 0; nt < 2; ++nt) {
#pragma unroll
        for (int t = 0; t < 4; ++t) {
            Bn[nt][t] = fragN[(nt * 4 + t) * 64 + lane];
            Bm[nt][t] = fragM[(nt * 4 + t) * 64 + lane];
        }
    }

    // -I fragments (fp8 0xB8 = -1.0 e4m3). Under the remap, tile0's diagonal
    // lives in hi=0 slots, tile1's in hi=1 slots: step t has -1 at byte
    // j = l31 - t*8 when 0 <= j < 8.  (Verified correct in round 9.)
    long If0[4], If1[4];
#pragma unroll
    for (int t = 0; t < 4; ++t) {
        const unsigned j = (unsigned)(l31 - t * 8);
        const long pat = (j < 8) ? (long)(0xB8ULL << (8 * j)) : 0L;
        If0[t] = hi ? 0L : pat;
        If1[t] = hi ? pat : 0L;
    }

    float l0 = 0.0f, l1 = 0.0f, l2 = 0.0f, l3 = 0.0f;

    int in_, im_, if_;
    {
        int s = blockIdx.x * SPB + wave * 32 + l31;
        in_ = pos_n[s]; im_ = pos_m[s]; if_ = pos_f[s];
    }

#pragma unroll 1
    for (int it = 0; it < iters; ++it) {
        const int in0 = in_, im0 = im_, if0 = if_;
        if (it + 1 < iters) {
            int s = ((it + 1) * NBLOCKS + blockIdx.x) * SPB + wave * 32 + l31;
            in_ = pos_n[s]; im_ = pos_m[s]; if_ = pos_f[s];
        }

        // ---- 6 independent dwordx4 gathers (32 contiguous B per lane).
        // Order: An, Ff, Am -- so Am is still in flight during n-tiles.
        const unsigned char* pn = nci8 + (long)in0 * 64 + hoff;
        const unsigned char* pf = fma8 + (long)if0 * 64 + hoff;
        const unsigned char* pm = nci8 + (long)im0 * 64 + hoff;

        ulonglong2 n01 = *(const ulonglong2*)pn;
        ulonglong2 n23 = *(const ulonglong2*)(pn + 16);
        ulonglong2 f01 = *(const ulonglong2*)pf;
        ulonglong2 f23 = *(const ulonglong2*)(pf + 16);
        ulonglong2 m01 = *(const ulonglong2*)pm;
        ulonglong2 m23 = *(const ulonglong2*)(pm + 16);

        const long An[4] = {(long)n01.x, (long)n01.y, (long)n23.x, (long)n23.y};
        const long Ff[4] = {(long)f01.x, (long)f01.y, (long)f23.x, (long)f23.y};
        const long Am[4] = {(long)m01.x, (long)m01.y, (long)m23.x, (long)m23.y};

        // ---- sequential tiles: one 16-reg accumulator live at a time.
        {   // n-loss, tile 0 (dims 0..31)
            floatx16 a{};
#pragma unroll
            for (int t = 0; t < 4; ++t)
                a = __builtin_amdgcn_mfma_f32_32x32x16_fp8_fp8(An[t], Bn[0][t], a, 0, 0, 0);
#pragma unroll
            for (int t = 0; t < 4; ++t)
                a = __builtin_amdgcn_mfma_f32_32x32x16_fp8_fp8(Ff[t], If0[t], a, 0, 0, 0);
#pragma unroll
            for (int r = 0; r < 16; r += 4) {
                l0 = fmaf(a[r],     a[r],     l0);
                l1 = fmaf(a[r + 1], a[r + 1], l1);
                l2 = fmaf(a[r + 2], a[r + 2], l2);
                l3 = fmaf(a[r + 3], a[r + 3], l3);
            }
        }
        {   // n-loss, tile 1 (dims 32..63)
            floatx16 a{};
#pragma unroll
            for (int t = 0; t < 4; ++t)
                a = __builtin_amdgcn_mfma_f32_32x32x16_fp8_fp8(An[t], Bn[1][t], a, 0, 0, 0);
#pragma unroll
            for (int t = 0; t < 4; ++t)
                a = __builtin_amdgcn_mfma_f32_32x32x16_fp8_fp8(Ff[t], If1[t], a, 0, 0, 0);
#pragma unroll
            for (int r = 0; r < 16; r += 4) {
                l0 = fmaf(a[r],     a[r],     l0);
                l1 = fmaf(a[r + 1], a[r + 1], l1);
                l2 = fmaf(a[r + 2], a[r + 2], l2);
                l3 = fmaf(a[r + 3], a[r + 3], l3);
            }
        }
        {   // m-loss, tile 0
            floatx16 a{};
#pragma unroll
            for (int t = 0; t < 4; ++t)
                a = __builtin_amdgcn_mfma_f32_32x32x16_fp8_fp8(Am[t], Bm[0][t], a, 0, 0, 0);
#pragma unroll
            for (int t = 0; t < 4; ++t)
                a = __builtin_amdgcn_mfma_f32_32x32x16_fp8_fp8(Ff[t], If0[t], a, 0, 0, 0);
#pragma unroll
            for (int r = 0; r < 16; r += 4) {
                l0 = fmaf(a[r],     a[r],     l0);
                l1 = fmaf(a[r + 1], a[r + 1], l1);
                l2 = fmaf(a[r + 2], a[r + 2], l2);
                l3 = fmaf(a[r + 3], a[r + 3], l3);
            }
        }
        {   // m-loss, tile 1
            floatx16 a{};
#pragma unroll
            for (int t = 0; t < 4; ++t)
                a = __builtin_amdgcn_mfma_f32_32x32x16_fp8_fp8(Am[t], Bm[1][t], a, 0, 0, 0);
#pragma unroll
            for (int t = 0; t < 4; ++t)
                a = __builtin_amdgcn_mfma_f32_32x32x16_fp8_fp8(Ff[t], If1[t], a, 0, 0, 0);
#pragma unroll
            for (int r = 0; r < 16; r += 4) {
                l0 = fmaf(a[r],     a[r],     l0);
                l1 = fmaf(a[r + 1], a[r + 1], l1);
                l2 = fmaf(a[r + 2], a[r + 2], l2);
                l3 = fmaf(a[r + 3], a[r + 3], l3);
            }
        }
    }

    float loss = (l0 + l1) + (l2 + l3);
#pragma unroll
    for (int o = 32; o > 0; o >>= 1) loss += __shfl_xor(loss, o, 64);

    // block-level reduction: 1 atomic per block instead of 4.
    __shared__ float red[4];
    if (lane == 0) red[wave] = loss;
    __syncthreads();
    if (threadIdx.x == 0)
        atomicAdd(out, (red[0] + red[1]) + (red[2] + red[3]));
}

// ---- fallback: fp32 tables with LDS staging (round-4 style), if ws too small.
#define ROW_BYTES 144
__global__ __launch_bounds__(256, 2) void ontomap_kernel_f32(
    const int* __restrict__ pos_n, const int* __restrict__ pos_m,
    const int* __restrict__ pos_f,
    const float* __restrict__ nci, const float* __restrict__ fma_emb,
    const float* __restrict__ n2f, const float* __restrict__ m2f,
    float* __restrict__ out, int iters)
{
    __shared__ char lds[4 * 2 * 32 * ROW_BYTES];

    const int lane = threadIdx.x & 63;
    const int wave = threadIdx.x >> 6;
    const int l31  = lane & 31;
    const int hi   = lane >> 5;
    const int kbase = hi * 8;
    const int srow   = lane >> 4;
    const int schunk = lane & 15;

    char* const nbase = lds + wave * (2 * 32 * ROW_BYTES);
    char* const mbase = nbase + 32 * ROW_BYTES;

    half8 Bn[2][4], Bm[2][4];
#pragma unroll
    for (int nt = 0; nt < 2; ++nt) {
#pragma unroll
        for (int t = 0; t < 4; ++t) {
            const float* p = n2f + (nt * 32 + l31) * 64 + t * 16 + kbase;
            Bn[nt][t] = cvt8(*(const float4*)p, *(const float4*)(p + 4));
            const float* q = m2f + (nt * 32 + l31) * 64 + t * 16 + kbase;
            Bm[nt][t] = cvt8(*(const float4*)q, *(const float4*)(q + 4));
        }
    }

    float loss = 0.0f;
    int in_, im_, if_;
    {
        int s = blockIdx.x * SPB + wave * 32 + l31;
        in_ = pos_n[s]; im_ = pos_m[s]; if_ = pos_f[s];
    }

#pragma unroll 1
    for (int it = 0; it < iters; ++it) {
        const int in0 = in_, im0 = im_, if0 = if_;
        if (it + 1 < iters) {
            int s = ((it + 1) * NBLOCKS + blockIdx.x) * SPB + wave * 32 + l31;
            in_ = pos_n[s]; im_ = pos_m[s]; if_ = pos_f[s];
        }

#pragma unroll
        for (int i = 0; i < 8; ++i) {
            const int rl = i * 4 + srow;
            const int rn = __shfl(in0, rl, 64);
            float4 v = ((const float4*)(nci + (long)rn * 64))[schunk];
            *(uint2*)(nbase + rl * ROW_BYTES + schunk * 8) = pack4(v);
            const int rm = __shfl(im0, rl, 64);
            float4 w = ((const float4*)(nci + (long)rm * 64))[schunk];
            *(uint2*)(mbase + rl * ROW_BYTES + schunk * 8) = pack4(w);
        }
        asm volatile("" ::: "memory");

        floatx16 aN0{}, aN1{}, aM0{}, aM1{};
#pragma unroll
        for (int t = 0; t < 4; ++t) {
            half8 aF = *(const half8*)(nbase + l31 * ROW_BYTES + t * 32 + hi * 16);
            aN0 = __builtin_amdgcn_mfma_f32_32x32x16_f16(aF, Bn[0][t], aN0, 0, 0, 0);
            aN1 = __builtin_amdgcn_mfma_f32_32x32x16_f16(aF, Bn[1][t], aN1, 0, 0, 0);
            half8 bF = *(const half8*)(mbase + l31 * ROW_BYTES + t * 32 + hi * 16);
            aM0 = __builtin_amdgcn_mfma_f32_32x32x16_f16(bF, Bm[0][t], aM0, 0, 0, 0);
            aM1 = __builtin_amdgcn_mfma_f32_32x32x16_f16(bF, Bm[1][t], aM1, 0, 0, 0);
        }

#pragma unroll
        for (int r = 0; r < 16; ++r) {
            const int mrow = (r & 3) + 8 * (r >> 2) + 4 * hi;
            const int fid  = __shfl(if0, mrow, 64);
            const float* pf = fma_emb + (long)fid * 64 + l31;
            const float f0 = pf[0];
            const float f1 = pf[32];
            float d;
            d = aN0[r] - f0; loss = fmaf(d, d, loss);
            d = aM0[r] - f0; loss = fmaf(d, d, loss);
            d = aN1[r] - f1; loss = fmaf(d, d, loss);
            d = aM1[r] - f1; loss = fmaf(d, d, loss);
        }
    }

#pragma unroll
    for (int o = 32; o > 0; o >>= 1) loss += __shfl_xor(loss, o, 64);
    if (lane == 0) atomicAdd(out, loss);
}

extern "C" void kernel_launch(void* const* d_in, const int* in_sizes, int n_in,
                              void* d_out, int out_size, void* d_ws, size_t ws_size,
                              hipStream_t stream) {
    const int*   pos_n   = (const int*)d_in[0];
    const int*   pos_m   = (const int*)d_in[1];
    const int*   pos_f   = (const int*)d_in[2];
    const float* nci_emb = (const float*)d_in[3];
    const float* fma_emb = (const float*)d_in[4];
    const float* n2f_mat = (const float*)d_in[5];
    const float* m2f_mat = (const float*)d_in[6];
    float* out = (float*)d_out;

    const int B = in_sizes[0];
    const int iters = B / (NBLOCKS * SPB);  // 1,048,576 -> 4

    const size_t TBL  = (size_t)NCI_ELEMS + (size_t)FMA_ELEMS;          // 16,000,000
    const size_t need = TBL + (size_t)FRAG_LONGS * sizeof(long);        // +8 KB
    if (ws_size >= need) {
        unsigned char* nci8 = (unsigned char*)d_ws;
        unsigned char* fma8 = nci8 + NCI_ELEMS;   // 9,600,000 is 64B-aligned
        long* fragN = (long*)(nci8 + TBL);        // 16,000,000 is 64B-aligned
        long* fragM = fragN + 8 * 64;
        convert_kernel<<<2048, 256, 0, stream>>>(
            (const float4*)nci_emb, (const float4*)fma_emb,
            (uint4*)nci8, (uint4*)fma8, out, n2f_mat, m2f_mat, fragN, fragM);
        ontomap_kernel_q<<<NBLOCKS, 256, 0, stream>>>(
            pos_n, pos_m, pos_f, nci8, fma8, fragN, fragM, out, iters);
    } else {
        (void)hipMemsetAsync(out, 0, sizeof(float), stream);
        ontomap_kernel_f32<<<NBLOCKS, 256, 0, stream>>>(
            pos_n, pos_m, pos_f, nci_emb, fma_emb, n2f_mat, m2f_mat, out, iters);
    }
}